// Round 5
// baseline (61.656 us; speedup 1.0000x reference)
//
#include <hip/hip_runtime.h>

#define M_TOT 32768
#define K_TOT 768
#define N_TOT 768

typedef int v4i __attribute__((ext_vector_type(4)));

#define GLOAD_LDS(g, l) __builtin_amdgcn_global_load_lds( \
    (const __attribute__((address_space(1))) unsigned int*)(g), \
    (__attribute__((address_space(3))) unsigned int*)(l), 16, 0, 0)

// Pack 4 int32 (each holding an int8 value) into one dword of 4 bytes. (verified R2)
__device__ __forceinline__ unsigned pack4(v4i a) {
  unsigned lo = __builtin_amdgcn_perm((unsigned)a.y, (unsigned)a.x, 0x00000400u);
  unsigned hi = __builtin_amdgcn_perm((unsigned)a.w, (unsigned)a.z, 0x00000400u);
  return __builtin_amdgcn_perm(hi, lo, 0x05040100u);
}

// W[k][n] int32 -> W8T[n][k] int8 (transposed, packed)
__global__ __launch_bounds__(256) void pack_w_kernel(const int* __restrict__ W,
                                                     signed char* __restrict__ W8T) {
  __shared__ signed char t[64][72];
  const int k0 = blockIdx.x * 64, n0 = blockIdx.y * 64;
  for (int i = threadIdx.x; i < 4096; i += 256) {
    int k = i >> 6, n = i & 63;
    t[n][k] = (signed char)W[(k0 + k) * N_TOT + n0 + n];
  }
  __syncthreads();
  for (int i = threadIdx.x; i < 4096; i += 256) {
    int n = i >> 6, k = i & 63;
    W8T[(n0 + n) * K_TOT + k0 + k] = t[n][k];
  }
}

// out_i32 = clamp(round((X@W)*alpha + bias))
// BM=64, BN=128, BK=64; 4 waves (2Mx2N), wave tile 32x64 via 2x4 mfma_i32_16x16x64.
// Depth-2 counted-vmcnt pipeline; per-stage vmem: 4 A dwordx4 + 2 B gload_lds.
// Ledger (in-order): steady TOP=vmcnt(4) [drain B(ks)], MID=vmcnt(6) [drain A(ks+1)].
// Small tile halves per-wave regs (acc 32 + q 32) -> 4 waves/SIMD -> 4 blocks/CU.
__global__ __launch_bounds__(256, 4) void gemm_i8_kernel(
    const int* __restrict__ X, const signed char* __restrict__ W8T,
    const float* __restrict__ bias, const float* __restrict__ alpha_p,
    int* __restrict__ out) {
  __shared__ __align__(16) signed char Abuf[2][4096];
  __shared__ __align__(16) signed char Bbuf[2][8192];

  // Bijective XCD-chunked swizzle: 3072 wgs = 8 XCDs x 384; nt fast so the 6
  // sibling N-tiles of one X M-panel share that XCD's L2.
  const int d = blockIdx.x;
  const int t = (d & 7) * 384 + (d >> 3);
  const int mt = t / 6, nt = t - mt * 6;
  const int row0 = mt << 6, col0 = nt << 7;

  const int tid = threadIdx.x;
  const int lane = tid & 63;
  const int wave = tid >> 6;
  const int wr = wave >> 1, wc = wave & 1;
  const int fr = lane & 15, fg = lane >> 4;
  const int fsw = (fr & 3) << 4;          // frag-read XOR swizzle

  // A loads: chunk j covers row rA = 16*j + (tid>>4) (j<4), int-cols (tid&15)*4..+4
  const int arow = tid >> 4;              // 0..15
  const int acol = (tid & 15) << 2;       // int col within 64-int stage
  const int* Xbase = X + (row0 + arow) * K_TOT + acol;
  const int awsw = (arow & 3) << 4;       // (16j+arow)&3 == arow&3

  // B gloads: chunk c = i*256+tid: row rB=c>>2, slot s=(c&3)*16; source
  // pre-swizzled so linear LDS + swizzled read agree (rule #21).
  int bsrc[2], bdst[2];
#pragma unroll
  for (int i = 0; i < 2; ++i) {
    int c = i * 256 + tid;
    int r = c >> 2, s = (c & 3) << 4;
    bsrc[i] = (col0 + r) * K_TOT + (s ^ ((r & 3) << 4));
    bdst[i] = i * 4096 + wave * 1024;     // wave-uniform base; HW adds lane*16
  }

  v4i q[2][4];
  const v4i zero = {0, 0, 0, 0};
  v4i acc[2][4];
#pragma unroll
  for (int m = 0; m < 2; ++m)
#pragma unroll
    for (int n = 0; n < 4; ++n) acc[m][n] = zero;

#define ISSUE_A(ks)                                                      \
  do {                                                                   \
    const int* _p = Xbase + (ks) * 64;                                   \
    _Pragma("unroll") for (int j = 0; j < 4; ++j)                        \
        q[(ks) & 1][j] = *(const v4i*)(_p + j * 16 * K_TOT);             \
  } while (0)

#define ISSUE_B(ks)                                                      \
  do {                                                                   \
    const signed char* _w = W8T + (ks) * 64;                             \
    signed char* _lb = Bbuf[(ks) & 1];                                   \
    GLOAD_LDS(_w + bsrc[0], _lb + bdst[0]);                              \
    GLOAD_LDS(_w + bsrc[1], _lb + bdst[1]);                              \
  } while (0)

#define PACK_WRITE_A(tt)                                                 \
  do {                                                                   \
    signed char* _ab = Abuf[(tt) & 1];                                   \
    _Pragma("unroll") for (int j = 0; j < 4; ++j) {                      \
      unsigned _dw = pack4(q[(tt) & 1][j]);                              \
      *(unsigned*)&_ab[(16 * j + arow) * 64 + (acol ^ awsw)] = _dw;      \
    }                                                                    \
  } while (0)

#define FRAGS_MFMA(ks)                                                   \
  do {                                                                   \
    v4i af[2], bf[4];                                                    \
    const signed char* _ab = Abuf[(ks) & 1];                             \
    const signed char* _bb = Bbuf[(ks) & 1];                             \
    const int _kb = (fg << 4) ^ fsw;                                     \
    _Pragma("unroll") for (int m = 0; m < 2; ++m)                        \
        af[m] = *(const v4i*)&_ab[(wr * 32 + m * 16 + fr) * 64 + _kb];   \
    _Pragma("unroll") for (int n = 0; n < 4; ++n)                        \
        bf[n] = *(const v4i*)&_bb[(wc * 64 + n * 16 + fr) * 64 + _kb];   \
    __builtin_amdgcn_s_setprio(1);                                       \
    _Pragma("unroll") for (int m = 0; m < 2; ++m)                        \
        _Pragma("unroll") for (int n = 0; n < 4; ++n)                    \
            acc[m][n] = __builtin_amdgcn_mfma_i32_16x16x64_i8(           \
                af[m], bf[n], acc[m][n], 0, 0, 0);                       \
    __builtin_amdgcn_s_setprio(0);                                       \
  } while (0)

  // GITER: top-wait (B(ks) + cross-wave A ds_writes) -> barrier -> issue
  // B(ks+1), A(ks+2) -> frags+MFMA(ks) -> mid-wait (A(ks+1) regs) -> pack+write.
#define GITER(ks, TOPW, MIDW)                                            \
  do {                                                                   \
    asm volatile("s_waitcnt vmcnt(" TOPW ") lgkmcnt(0)" ::: "memory");   \
    __builtin_amdgcn_s_barrier();                                        \
    if ((ks) + 1 < 12) ISSUE_B((ks) + 1);                                \
    if ((ks) + 2 < 12) ISSUE_A((ks) + 2);                                \
    FRAGS_MFMA(ks);                                                      \
    if ((ks) + 1 < 12) {                                                 \
      asm volatile("s_waitcnt vmcnt(" MIDW ")" ::: "memory");            \
      PACK_WRITE_A((ks) + 1);                                            \
    }                                                                    \
  } while (0)

  // Prologue: B(0),A(0),A(1) in flight; wait A(0) (leave A(1)=4); pack A(0).
  ISSUE_B(0); ISSUE_A(0); ISSUE_A(1);
  asm volatile("s_waitcnt vmcnt(4)" ::: "memory");
  PACK_WRITE_A(0);

  // Ledger (6 vmem/stage: B=2 then A=4): steady TOP=4, MID=6.
  // ks=10: TOP=4, MID=2 (only B(11) outstanding). ks=11: TOP=0.
  GITER(0, "4", "6");
  GITER(1, "4", "6");
  GITER(2, "4", "6");
  GITER(3, "4", "6");
  GITER(4, "4", "6");
  GITER(5, "4", "6");
  GITER(6, "4", "6");
  GITER(7, "4", "6");
  GITER(8, "4", "6");
  GITER(9, "4", "6");
  GITER(10, "4", "2");
  GITER(11, "0", "0");

  // Epilogue: C/D layout col = lane&15, row = (lane>>4)*4 + reg. Output int32.
  const float alpha = *alpha_p;
  float bv[4];
#pragma unroll
  for (int n = 0; n < 4; ++n) bv[n] = bias[col0 + wc * 64 + n * 16 + fr];

#pragma unroll
  for (int m = 0; m < 2; ++m) {
    int orow = row0 + wr * 32 + m * 16 + fg * 4;
#pragma unroll
    for (int n = 0; n < 4; ++n) {
      int ocol = col0 + wc * 64 + n * 16 + fr;
      int* po = out + orow * N_TOT + ocol;
#pragma unroll
      for (int r = 0; r < 4; ++r) {
        float v = rintf((float)acc[m][n][r] * alpha + bv[n]);
        v = fminf(127.f, fmaxf(-128.f, v));
        po[r * N_TOT] = (int)v;
      }
    }
  }
}

extern "C" void kernel_launch(void* const* d_in, const int* in_sizes, int n_in,
                              void* d_out, int out_size, void* d_ws, size_t ws_size,
                              hipStream_t stream) {
  const int* X = (const int*)d_in[0];        // [4,8192,768] int8 promoted to int32
  const int* W = (const int*)d_in[1];        // [768,768] int8 promoted to int32
  const float* bias = (const float*)d_in[2]; // [1,768] fp16 promoted to float32
  const float* alpha = (const float*)d_in[3];
  int* out = (int*)d_out;                    // int8 output promoted to int32
  signed char* W8T = (signed char*)d_ws;     // 768*768 = 589,824 B scratch

  dim3 pg(K_TOT / 64, N_TOT / 64);
  pack_w_kernel<<<pg, 256, 0, stream>>>(W, W8T);
  gemm_i8_kernel<<<(M_TOT / 64) * (N_TOT / 128), 256, 0, stream>>>(X, W8T, bias, alpha, out);
}

// Round 6
// 58.466 us; speedup vs baseline: 1.0546x; 1.0546x over previous
//
#include <hip/hip_runtime.h>

#define M_TOT 32768
#define K_TOT 768
#define N_TOT 768

typedef int v4i __attribute__((ext_vector_type(4)));

#define GLOAD_LDS(g, l) __builtin_amdgcn_global_load_lds( \
    (const __attribute__((address_space(1))) unsigned int*)(g), \
    (__attribute__((address_space(3))) unsigned int*)(l), 16, 0, 0)

// Pack 4 int32 (each holding an int8 value) into one dword of 4 bytes. (verified R2)
__device__ __forceinline__ unsigned pack4(v4i a) {
  unsigned lo = __builtin_amdgcn_perm((unsigned)a.y, (unsigned)a.x, 0x00000400u);
  unsigned hi = __builtin_amdgcn_perm((unsigned)a.w, (unsigned)a.z, 0x00000400u);
  return __builtin_amdgcn_perm(hi, lo, 0x05040100u);
}

// W[k][n] int32 -> W8T[n][k] int8 (transposed, packed)
__global__ __launch_bounds__(256) void pack_w_kernel(const int* __restrict__ W,
                                                     signed char* __restrict__ W8T) {
  __shared__ signed char t[64][72];
  const int k0 = blockIdx.x * 64, n0 = blockIdx.y * 64;
  for (int i = threadIdx.x; i < 4096; i += 256) {
    int k = i >> 6, n = i & 63;
    t[n][k] = (signed char)W[(k0 + k) * N_TOT + n0 + n];
  }
  __syncthreads();
  for (int i = threadIdx.x; i < 4096; i += 256) {
    int n = i >> 6, k = i & 63;
    W8T[(n0 + n) * K_TOT + k0 + k] = t[n][k];
  }
}

// out_i32 = clamp(round((X@W)*alpha + bias))
// BM=128, BN=128, BK=64; 512 thr = 8 waves (4Mx2N), wave tile 32x64 (2x4 mfma).
// Same 64-MFMA-per-barrier density as R4 at half the per-wave registers:
// single-buffered q[4] (pack(k+1) then reuse regs for issue(k+2)), acc 32 AGPR.
// Ledger (stage = 1 B gload_lds + 4 A dwordx4, A issued last):
//   top  vmcnt(4): outstanding [B(k), A(k+1)x4] -> drains B(k)
//   mid  vmcnt(1): outstanding [A(k+1)x4, B(k+1)] -> drains A(k+1)
__global__ __launch_bounds__(512, 4) void gemm_i8_kernel(
    const int* __restrict__ X, const signed char* __restrict__ W8T,
    const float* __restrict__ bias, const float* __restrict__ alpha_p,
    int* __restrict__ out) {
  __shared__ __align__(16) signed char Abuf[2][8192];
  __shared__ __align__(16) signed char Bbuf[2][8192];

  // Bijective XCD-chunked swizzle: 1536 wgs = 8 XCDs x 192; nt fast so the 6
  // sibling N-tiles of one X M-panel share that XCD's L2.
  const int d = blockIdx.x;
  const int t = (d & 7) * 192 + (d >> 3);
  const int mt = t / 6, nt = t - mt * 6;
  const int row0 = mt << 7, col0 = nt << 7;

  const int tid = threadIdx.x;
  const int lane = tid & 63;
  const int wave = tid >> 6;              // 0..7
  const int wr = wave >> 1, wc = wave & 1;
  const int fr = lane & 15, fg = lane >> 4;
  const int fsw = (fr & 3) << 4;          // frag-read XOR swizzle

  // A loads: thread covers rows 32j + arow (j=0..3), int-cols acol..acol+4.
  // Per instr: 4 consecutive rows x 256B contiguous = fully coalesced.
  const int arow = tid >> 4;              // 0..31
  const int acol = (tid & 15) << 2;       // int col within 64-int stage
  const int* Xbase = X + (row0 + arow) * K_TOT + acol;
  const int awsw = (arow & 3) << 4;       // (32j+arow)&3 == arow&3

  // B gload_lds: thread covers row tid>>2, 16B slot (tid&3)*16; source
  // pre-swizzled so linear LDS + swizzled read agree (rule #21).
  const int bsrc = (col0 + (tid >> 2)) * K_TOT +
                   (((tid & 3) << 4) ^ (((tid >> 2) & 3) << 4));
  const int bdst = wave * 1024;           // wave-uniform base; HW adds lane*16

  v4i q[4];
  const v4i zero = {0, 0, 0, 0};
  v4i acc[2][4];
#pragma unroll
  for (int m = 0; m < 2; ++m)
#pragma unroll
    for (int n = 0; n < 4; ++n) acc[m][n] = zero;

#define ISSUE_A(ks)                                                      \
  do {                                                                   \
    const int* _p = Xbase + (ks) * 64;                                   \
    _Pragma("unroll") for (int j = 0; j < 4; ++j)                        \
        q[j] = *(const v4i*)(_p + j * 32 * K_TOT);                       \
  } while (0)

#define ISSUE_B(ks)                                                      \
  GLOAD_LDS(W8T + (ks) * 64 + bsrc, &Bbuf[(ks) & 1][bdst])

#define PACK_WRITE_A(tt)                                                 \
  do {                                                                   \
    signed char* _ab = Abuf[(tt) & 1];                                   \
    _Pragma("unroll") for (int j = 0; j < 4; ++j) {                      \
      unsigned _dw = pack4(q[j]);                                        \
      *(unsigned*)&_ab[(32 * j + arow) * 64 + (acol ^ awsw)] = _dw;      \
    }                                                                    \
  } while (0)

#define FRAGS_MFMA(ks)                                                   \
  do {                                                                   \
    v4i af[2], bf[4];                                                    \
    const signed char* _ab = Abuf[(ks) & 1];                             \
    const signed char* _bb = Bbuf[(ks) & 1];                             \
    const int _kb = (fg << 4) ^ fsw;                                     \
    _Pragma("unroll") for (int m = 0; m < 2; ++m)                        \
        af[m] = *(const v4i*)&_ab[(wr * 32 + m * 16 + fr) * 64 + _kb];   \
    _Pragma("unroll") for (int n = 0; n < 4; ++n)                        \
        bf[n] = *(const v4i*)&_bb[(wc * 64 + n * 16 + fr) * 64 + _kb];   \
    __builtin_amdgcn_s_setprio(1);                                       \
    _Pragma("unroll") for (int m = 0; m < 2; ++m)                        \
        _Pragma("unroll") for (int n = 0; n < 4; ++n)                    \
            acc[m][n] = __builtin_amdgcn_mfma_i32_16x16x64_i8(           \
                af[m], bf[n], acc[m][n], 0, 0, 0);                       \
    __builtin_amdgcn_s_setprio(0);                                       \
  } while (0)

  // GITER: top-wait (drain B(ks); own A-ds_writes via lgkm) -> barrier ->
  // issue B(ks+1) -> MFMA(ks) -> mid-wait (drain A(ks+1) regs) -> pack ->
  // issue A(ks+2) into freed q.
#define GITER(ks, TOPW)                                                  \
  do {                                                                   \
    asm volatile("s_waitcnt vmcnt(" TOPW ") lgkmcnt(0)" ::: "memory");   \
    __builtin_amdgcn_s_barrier();                                        \
    if ((ks) + 1 < 12) ISSUE_B((ks) + 1);                                \
    FRAGS_MFMA(ks);                                                      \
    if ((ks) + 1 < 12) {                                                 \
      asm volatile("s_waitcnt vmcnt(1)" ::: "memory");                   \
      PACK_WRITE_A((ks) + 1);                                            \
      if ((ks) + 2 < 12) ISSUE_A((ks) + 2);                              \
    }                                                                    \
  } while (0)

  // Prologue: A(0) then B(0) in flight; drain A(0) (leave B(0)); pack A(0);
  // issue A(1). Queue entering iter 0: [B(0), A(1)x4] -> matches steady top.
  ISSUE_A(0);
  ISSUE_B(0);
  asm volatile("s_waitcnt vmcnt(1)" ::: "memory");
  PACK_WRITE_A(0);
  ISSUE_A(1);

  GITER(0, "4");
  GITER(1, "4");
  GITER(2, "4");
  GITER(3, "4");
  GITER(4, "4");
  GITER(5, "4");
  GITER(6, "4");
  GITER(7, "4");
  GITER(8, "4");
  GITER(9, "4");
  GITER(10, "4");
  GITER(11, "0");

  // Epilogue: C/D layout col = lane&15, row = (lane>>4)*4 + reg. Output int32.
  const float alpha = *alpha_p;
  float bv[4];
#pragma unroll
  for (int n = 0; n < 4; ++n) bv[n] = bias[col0 + wc * 64 + n * 16 + fr];

#pragma unroll
  for (int m = 0; m < 2; ++m) {
    int orow = row0 + wr * 32 + m * 16 + fg * 4;
#pragma unroll
    for (int n = 0; n < 4; ++n) {
      int ocol = col0 + wc * 64 + n * 16 + fr;
      int* po = out + orow * N_TOT + ocol;
#pragma unroll
      for (int r = 0; r < 4; ++r) {
        float v = rintf((float)acc[m][n][r] * alpha + bv[n]);
        v = fminf(127.f, fmaxf(-128.f, v));
        po[r * N_TOT] = (int)v;
      }
    }
  }
}

extern "C" void kernel_launch(void* const* d_in, const int* in_sizes, int n_in,
                              void* d_out, int out_size, void* d_ws, size_t ws_size,
                              hipStream_t stream) {
  const int* X = (const int*)d_in[0];        // [4,8192,768] int8 promoted to int32
  const int* W = (const int*)d_in[1];        // [768,768] int8 promoted to int32
  const float* bias = (const float*)d_in[2]; // [1,768] fp16 promoted to float32
  const float* alpha = (const float*)d_in[3];
  int* out = (int*)d_out;                    // int8 output promoted to int32
  signed char* W8T = (signed char*)d_ws;     // 768*768 = 589,824 B scratch

  dim3 pg(K_TOT / 64, N_TOT / 64);
  pack_w_kernel<<<pg, 256, 0, stream>>>(W, W8T);
  gemm_i8_kernel<<<(M_TOT / 128) * (N_TOT / 128), 512, 0, stream>>>(X, W8T, bias, alpha, out);
}